// Round 2
// baseline (225.708 us; speedup 1.0000x reference)
//
#include <hip/hip_runtime.h>
#include <hip/hip_bf16.h>

// C[32768,2304] = A[32768,768] * W^T + b ; outputs split into q,k,v [32768,768] fp32.
#define M_TOT 32768
#define K_TOT 768
#define N_TOT 2304
#define H     768
#define BM 256
#define BN 256
#define BK 64
#define NBN 9                    // N_TOT/BN
#define NBM 128                  // M_TOT/BM
#define NBLK (NBM*NBN)           // 1152 (divisible by 8 -> simple XCD swizzle valid)
#define NKT  (K_TOT/BK)          // 12
#define OUT_PER 25165824         // M_TOT*H

typedef __attribute__((ext_vector_type(8))) short bf16x8;
typedef __attribute__((ext_vector_type(4))) float f32x4;

__device__ __forceinline__ void gld_lds16(const void* g, void* l) {
    __builtin_amdgcn_global_load_lds(
        (const __attribute__((address_space(1))) unsigned int*)g,
        (__attribute__((address_space(3))) unsigned int*)l,
        16, 0, 0);
}

__device__ __forceinline__ unsigned short f2bf_rne(float f) {
    unsigned u = __builtin_bit_cast(unsigned, f);
    unsigned r = (u + 0x7FFFu + ((u >> 16) & 1u)) >> 16;
    return (unsigned short)r;
}

// ---------------------------------------------------------------------------
// Pass 1: fp32 -> bf16 convert of A and the three weights; pack biases.
// (measured ~21 us ~= its 161 MB roofline — leave as-is)
// ---------------------------------------------------------------------------
__global__ void convert_pack(const float* __restrict__ A,
                             const float* __restrict__ wq, const float* __restrict__ wk,
                             const float* __restrict__ wv,
                             const float* __restrict__ bq, const float* __restrict__ bk,
                             const float* __restrict__ bv,
                             unsigned short* __restrict__ Ab,
                             unsigned short* __restrict__ Wb,
                             float* __restrict__ biasb) {
    const int NA4 = (M_TOT * K_TOT) / 4;
    const int NW4 = (H * H) / 4;
    const int total = NA4 + 3 * NW4;

    int tid = blockIdx.x * blockDim.x + threadIdx.x;
    if (tid < 2304) {
        biasb[tid] = (tid < 768) ? bq[tid] : (tid < 1536) ? bk[tid - 768] : bv[tid - 1536];
    }
    const int stride = gridDim.x * blockDim.x;
    for (int i = tid; i < total; i += stride) {
        const float* src; unsigned short* dst; int idx;
        if (i < NA4) { src = A; dst = Ab; idx = i; }
        else {
            int j = i - NA4; int w = j / NW4; idx = j - w * NW4;
            src = (w == 0) ? wq : (w == 1) ? wk : wv;
            dst = Wb + (size_t)w * (H * H);
        }
        float4 v = reinterpret_cast<const float4*>(src)[idx];
        ushort4 o;
        o.x = f2bf_rne(v.x); o.y = f2bf_rne(v.y);
        o.z = f2bf_rne(v.z); o.w = f2bf_rne(v.w);
        reinterpret_cast<ushort4*>(dst)[idx] = o;
    }
}

// ---------------------------------------------------------------------------
// Pass 2: 256x256 bf16 MFMA GEMM, counted-vmcnt pipelined structure:
//   512 thr = 8 waves (2M x 4N), wave tile 128x64 (acc[8][4] f32x4).
//   2-buffer LDS (128 KiB), raw s_barrier, vmcnt(8) (never 0 in main loop),
//   4 quadrant-phases/K-tile: 12 ds_read_b128 -> setprio(1) 16 MFMA setprio(0).
//   LDS (R&7) XOR swizzle: linear gld_lds dest + pre-swizzled global source
//   + XOR'd read addr (rule 21: same involution both sides).
// ---------------------------------------------------------------------------
__global__ __launch_bounds__(512, 2) void qkv_gemm(
        const unsigned short* __restrict__ Ab,
        const unsigned short* __restrict__ Wb,
        const float* __restrict__ bias,
        float* __restrict__ out) {

    __shared__ __align__(16) unsigned short sA[2][BM * BK];  // 64 KiB
    __shared__ __align__(16) unsigned short sB[2][BN * BK];  // 64 KiB

    const int tid  = threadIdx.x;
    const int lane = tid & 63;
    const int wid  = tid >> 6;     // 0..7
    const int wm   = wid >> 2;     // 0..1 : rows wm*128..+127
    const int wn   = wid & 3;      // 0..3 : cols wn*64..+63

    // XCD-aware swizzle (bijective since NBLK % 8 == 0)
    int bid = (int)blockIdx.x;
    bid = (bid & 7) * (NBLK / 8) + (bid >> 3);
    const int bm = bid / NBN;
    const int bn = bid - bm * NBN;
    const int m0 = bm * BM;
    const int n0 = bn * BN;

    // ---- staging addresses: chunk c = i*512+tid ; R=c>>3, slot=c&7.
    // LDS[R][slot] holds global cols [(slot^(R&7))*8 .. +8)  (source pre-swizzle)
    const unsigned short* aSrc[4];
    const unsigned short* bSrc[4];
    int dOff[4];
    #pragma unroll
    for (int i = 0; i < 4; ++i) {
        int c = i * 512 + tid;
        int R = c >> 3, s = c & 7;
        int cs = (s ^ (R & 7)) << 3;
        aSrc[i] = Ab + (size_t)(m0 + R) * K_TOT + cs;
        bSrc[i] = Wb + (size_t)(n0 + R) * K_TOT + cs;
        dOff[i] = c << 3;            // linear LDS element offset
    }

    // ---- ds_read byte offsets. Fragment: row = base + (lane&15),
    // col = kk*32 + (lane>>4)*8, read at col ^ ((R&7)<<3); R&7 == lane&7 here.
    const int colr = (lane >> 4) << 3;
    const int fx   = (lane & 7) << 3;
    const int aOff0 = (((wm * 128 + (lane & 15)) * BK) + (colr ^ fx)) * 2;
    const int aOff1 = aOff0 ^ 64;   // kk=1: col+32 -> byte XOR 64 (bit5 of elem col)
    const int bOff0 = (((wn * 64 + (lane & 15)) * BK) + (colr ^ fx)) * 2;
    const int bOff1 = bOff0 ^ 64;

    f32x4 acc[8][4];
    #pragma unroll
    for (int i = 0; i < 8; ++i)
        #pragma unroll
        for (int j = 0; j < 4; ++j)
            acc[i][j] = (f32x4){0.f, 0.f, 0.f, 0.f};

    // stage one K-tile (A:4 + B:4 loads per thread) into buffer b
    auto stage = [&](int kt, int b) {
        const int ko = kt * BK;
        #pragma unroll
        for (int i = 0; i < 4; ++i) gld_lds16(aSrc[i] + ko, &sA[b][dOff[i]]);
        #pragma unroll
        for (int i = 0; i < 4; ++i) gld_lds16(bSrc[i] + ko, &sB[b][dOff[i]]);
    };

    stage(0, 0);
    stage(1, 1);

    for (int kt = 0; kt < NKT; ++kt) {
        const int b = kt & 1;
        // tile kt landed when <= 8 loads (tile kt+1) outstanding
        if (kt < NKT - 1) { asm volatile("s_waitcnt vmcnt(8)" ::: "memory"); }
        else              { asm volatile("s_waitcnt vmcnt(0)" ::: "memory"); }
        __builtin_amdgcn_sched_barrier(0);
        __builtin_amdgcn_s_barrier();
        __builtin_amdgcn_sched_barrier(0);

        const char* pA = (const char*)&sA[b][0];
        const char* pB = (const char*)&sB[b][0];

        #pragma unroll
        for (int ph = 0; ph < 4; ++ph) {
            const int qm = ph >> 1, qn = ph & 1;
            bf16x8 af[4][2], bfv[2][2];
            #pragma unroll
            for (int mi = 0; mi < 4; ++mi) {
                const char* p = pA + qm * 8192 + mi * 2048;   // qm*64 rows, mi*16 rows
                af[mi][0] = *(const bf16x8*)(p + aOff0);
                af[mi][1] = *(const bf16x8*)(p + aOff1);
            }
            #pragma unroll
            for (int nj = 0; nj < 2; ++nj) {
                const char* p = pB + qn * 4096 + nj * 2048;   // qn*32 rows, nj*16 rows
                bfv[nj][0] = *(const bf16x8*)(p + bOff0);
                bfv[nj][1] = *(const bf16x8*)(p + bOff1);
            }
            __builtin_amdgcn_s_setprio(1);
            #pragma unroll
            for (int kk = 0; kk < 2; ++kk)
                #pragma unroll
                for (int mi = 0; mi < 4; ++mi)
                    #pragma unroll
                    for (int nj = 0; nj < 2; ++nj)
                        acc[qm * 4 + mi][qn * 2 + nj] =
                            __builtin_amdgcn_mfma_f32_16x16x32_bf16(
                                af[mi][kk], bfv[nj][kk],
                                acc[qm * 4 + mi][qn * 2 + nj], 0, 0, 0);
            __builtin_amdgcn_s_setprio(0);
            __builtin_amdgcn_sched_barrier(0);
        }

        // all waves done reading buf b (ds_reads retired via lgkmcnt before MFMA)
        asm volatile("" ::: "memory");
        __builtin_amdgcn_s_barrier();
        __builtin_amdgcn_sched_barrier(0);
        if (kt + 2 < NKT) stage(kt + 2, b);   // prefetch into the buffer just freed
    }

    // ---- epilogue: C/D layout col=lane&15, row=(lane>>4)*4+reg (m89-verified)
    const int which = n0 / H;          // BN=256: tile always inside one of q/k/v
    const int c0    = n0 - which * H;
    float* outB = out + (size_t)which * OUT_PER;

    #pragma unroll
    for (int j = 0; j < 4; ++j) {
        const int nl  = wn * 64 + j * 16 + (lane & 15);
        const float bv = bias[n0 + nl];
        const int col  = c0 + nl;
        #pragma unroll
        for (int i = 0; i < 8; ++i) {
            const int mrow = m0 + wm * 128 + i * 16 + ((lane >> 4) << 2);
            #pragma unroll
            for (int r = 0; r < 4; ++r)
                outB[(size_t)(mrow + r) * H + col] = acc[i][j][r] + bv;
        }
    }
}

extern "C" void kernel_launch(void* const* d_in, const int* in_sizes, int n_in,
                              void* d_out, int out_size, void* d_ws, size_t ws_size,
                              hipStream_t stream) {
    const float* hs = (const float*)d_in[0];
    const float* wq = (const float*)d_in[1];
    const float* bq = (const float*)d_in[2];
    const float* wk = (const float*)d_in[3];
    const float* bk = (const float*)d_in[4];
    const float* wv = (const float*)d_in[5];
    const float* bv = (const float*)d_in[6];

    unsigned short* Ab = (unsigned short*)d_ws;
    unsigned short* Wb = Ab + (size_t)M_TOT * K_TOT;
    float* biasb       = (float*)(Wb + (size_t)N_TOT * K_TOT);

    hipLaunchKernelGGL(convert_pack, dim3(2048), dim3(256), 0, stream,
                       hs, wq, wk, wv, bq, bk, bv, Ab, Wb, biasb);

    hipLaunchKernelGGL(qkv_gemm, dim3(NBLK), dim3(512), 0, stream,
                       Ab, Wb, biasb, (float*)d_out);
}

// Round 3
// 200.011 us; speedup vs baseline: 1.1285x; 1.1285x over previous
//
#include <hip/hip_runtime.h>
#include <hip/hip_bf16.h>

// C[32768,2304] = A[32768,768] * W^T + b ; outputs q,k,v [32768,768] fp32 each.
#define M_TOT 32768
#define K_TOT 768
#define N_TOT 2304
#define H     768
#define BM 128
#define BN 128
#define BK 64
#define NBN 18                   // N_TOT/BN
#define NBM 256                  // M_TOT/BM
#define NBLK (NBM*NBN)           // 4608, % 8 == 0 -> simple XCD swizzle bijective
#define NKT  (K_TOT/BK)          // 12
#define TILE_ELEMS 8192          // 128 rows x 64 k
#define OUT_PER 25165824         // M_TOT*H

typedef __attribute__((ext_vector_type(8))) short bf16x8;
typedef __attribute__((ext_vector_type(8))) unsigned short u16x8;
typedef __attribute__((ext_vector_type(4))) float f32x4;

__device__ __forceinline__ void gld_lds16(const void* g, void* l) {
    __builtin_amdgcn_global_load_lds(
        (const __attribute__((address_space(1))) unsigned int*)g,
        (__attribute__((address_space(3))) unsigned int*)l,
        16, 0, 0);
}

__device__ __forceinline__ unsigned short f2bf_rne(float f) {
    unsigned u = __builtin_bit_cast(unsigned, f);
    unsigned r = (u + 0x7FFFu + ((u >> 16) & 1u)) >> 16;
    return (unsigned short)r;
}

// ---------------------------------------------------------------------------
// Pass 1: fp32 -> bf16 convert + PACK into the LDS-ready tiled layout:
//   pk[tile][kb][row][k7]  with tile = (rowTile, kt), kb=k-octet 0..7,
//   row 0..127, k7 0..7.  One block packs one 128x64 tile via an LDS bounce
//   (coalesced fp32 reads, coalesced 16B bf16 writes).
//   A: 256*12 = 3072 tiles; W(concat q,k,v): 18*12 = 216 tiles.
// ---------------------------------------------------------------------------
#define A_TILES 3072
#define W_TILES 216
#define LDSW 68                  // padded fp32 row stride (16B-aligned, de-conflicted)

__global__ void convert_pack(const float* __restrict__ A,
                             const float* __restrict__ wq, const float* __restrict__ wk,
                             const float* __restrict__ wv,
                             const float* __restrict__ bq, const float* __restrict__ bk,
                             const float* __restrict__ bv,
                             unsigned short* __restrict__ A_pk,
                             unsigned short* __restrict__ W_pk,
                             float* __restrict__ biasb) {
    __shared__ float lds_f[128 * LDSW];

    const int tid = threadIdx.x;
    const int t   = blockIdx.x;

    int gt = t * 256 + tid;
    if (gt < 2304) {
        biasb[gt] = (gt < 768) ? bq[gt] : (gt < 1536) ? bk[gt - 768] : bv[gt - 1536];
    }

    const float* src;
    unsigned short* dst;
    if (t < A_TILES) {
        const int mt = t / NKT, kt = t - mt * NKT;
        src = A + (size_t)mt * 128 * K_TOT + kt * BK;
        dst = A_pk + (size_t)t * TILE_ELEMS;
    } else {
        const int t2 = t - A_TILES;            // 0..215
        const int nt = t2 / NKT, kt = t2 - nt * NKT;
        const int which = nt / 6;
        const int row0  = (nt - which * 6) * 128;
        const float* w = (which == 0) ? wq : (which == 1) ? wk : wv;
        src = w + (size_t)row0 * K_TOT + kt * BK;
        dst = W_pk + (size_t)t2 * TILE_ELEMS;
    }

    // read: 128 rows x 16 float4 = 2048 chunks, 8 per thread
    #pragma unroll
    for (int j = 0; j < 8; ++j) {
        int f = j * 256 + tid;
        int row = f >> 4, c4 = f & 15;
        float4 v = *reinterpret_cast<const float4*>(src + (size_t)row * K_TOT + c4 * 4);
        *reinterpret_cast<float4*>(&lds_f[row * LDSW + c4 * 4]) = v;
    }
    __syncthreads();

    // write: 1024 x 16B chunks, 4 per thread; chunk c -> kb=c>>7, row=c&127
    #pragma unroll
    for (int j = 0; j < 4; ++j) {
        int c = j * 256 + tid;
        int kb = c >> 7, row = c & 127;
        const float* p = &lds_f[row * LDSW + kb * 8];
        u16x8 o;
        #pragma unroll
        for (int e = 0; e < 8; ++e) o[e] = f2bf_rne(p[e]);
        *reinterpret_cast<u16x8*>(dst + (size_t)c * 8) = o;
    }
}

// ---------------------------------------------------------------------------
// Pass 2: 128x128 bf16 MFMA GEMM (m97 2-phase structure, proven 183us base):
//   - staging: fully linear gld_lds16 from packed layout (perfect coalescing)
//   - LDS packed [kb][row][8]: fragment ds_read_b128 is 16-lane-contiguous
//     256B blocks -> bank-conflict-free by construction (no swizzle)
//   - operand-swap mfma(bf, af): lane's 4 acc regs = 4 consecutive n
//     -> float4 epilogue stores (16 instead of 64 store instrs/thread)
// ---------------------------------------------------------------------------
__global__ __launch_bounds__(256, 4) void qkv_gemm(
        const unsigned short* __restrict__ A_pk,
        const unsigned short* __restrict__ W_pk,
        const float* __restrict__ bias,
        float* __restrict__ out) {

    __shared__ __align__(16) unsigned short sA[TILE_ELEMS];
    __shared__ __align__(16) unsigned short sB[TILE_ELEMS];

    const int tid  = threadIdx.x;
    const int lane = tid & 63;
    const int wid  = tid >> 6;
    const int wr   = wid >> 1;       // 0..1 : rows wr*64..+63
    const int wc   = wid & 1;        // 0..1 : cols wc*64..+63

    int bid = (int)blockIdx.x;
    bid = (bid & 7) * (NBLK / 8) + (bid >> 3);     // XCD-aware (bijective)
    const int bm = bid / NBN;
    const int bn = bid - bm * NBN;
    const int m0 = bm * BM;
    const int n0 = bn * BN;

    f32x4 acc[4][4];
    #pragma unroll
    for (int i = 0; i < 4; i++)
        #pragma unroll
        for (int j = 0; j < 4; j++)
            acc[i][j] = (f32x4){0.f, 0.f, 0.f, 0.f};

    // staging: 1024 chunks of 16B per tile; thread handles c = i*256+tid, linear
    const unsigned short* aT = A_pk + (size_t)bm * NKT * TILE_ELEMS;
    const unsigned short* bT = W_pk + (size_t)bn * NKT * TILE_ELEMS;

    // fragment read offsets (bytes) in packed LDS [kb][row][8]:
    //   elem = (kk*4 + (lane>>4))*1024 + row*8 + j
    const int aBase = (((lane >> 4) << 10) + (wr * 64 + (lane & 15)) * 8) * 2;
    const int bBase = (((lane >> 4) << 10) + (wc * 64 + (lane & 15)) * 8) * 2;

    for (int kt = 0; kt < NKT; ++kt) {
        if (kt) __syncthreads();
        const unsigned short* aS = aT + kt * TILE_ELEMS;
        const unsigned short* bS = bT + kt * TILE_ELEMS;
        #pragma unroll
        for (int i = 0; i < 4; i++) {
            const int c = i * 256 + tid;
            gld_lds16(aS + c * 8, &sA[c * 8]);
            gld_lds16(bS + c * 8, &sB[c * 8]);
        }
        __syncthreads();

        #pragma unroll
        for (int kk = 0; kk < 2; kk++) {
            bf16x8 af[4], bf[4];
            #pragma unroll
            for (int i = 0; i < 4; i++)
                af[i] = *reinterpret_cast<const bf16x8*>(
                    (const char*)sA + aBase + i * 256 + kk * 8192);
            #pragma unroll
            for (int j = 0; j < 4; j++)
                bf[j] = *reinterpret_cast<const bf16x8*>(
                    (const char*)sB + bBase + j * 256 + kk * 8192);
            #pragma unroll
            for (int i = 0; i < 4; i++)
                #pragma unroll
                for (int j = 0; j < 4; j++)
                    // swapped operands: D.col(lane&15)=A-row(m), D.row(reg)=W-row(n)
                    acc[i][j] = __builtin_amdgcn_mfma_f32_16x16x32_bf16(
                        bf[j], af[i], acc[i][j], 0, 0, 0);
        }
    }

    // epilogue: lane holds m = frag_m0 + (lane&15), n = frag_n0 + (lane>>4)*4 + reg
    const int which = n0 / H;
    const int c0    = n0 - which * H;
    float* outB = out + (size_t)which * OUT_PER;

    #pragma unroll
    for (int j = 0; j < 4; ++j) {
        const int ncol = wc * 64 + j * 16 + ((lane >> 4) << 2);
        const float4 bv4 = *reinterpret_cast<const float4*>(&bias[n0 + ncol]);
        #pragma unroll
        for (int i = 0; i < 4; ++i) {
            const int mrow = m0 + wr * 64 + i * 16 + (lane & 15);
            float4 o;
            o.x = acc[i][j][0] + bv4.x;
            o.y = acc[i][j][1] + bv4.y;
            o.z = acc[i][j][2] + bv4.z;
            o.w = acc[i][j][3] + bv4.w;
            *reinterpret_cast<float4*>(&outB[(size_t)mrow * H + c0 + ncol]) = o;
        }
    }
}

extern "C" void kernel_launch(void* const* d_in, const int* in_sizes, int n_in,
                              void* d_out, int out_size, void* d_ws, size_t ws_size,
                              hipStream_t stream) {
    const float* hs = (const float*)d_in[0];
    const float* wq = (const float*)d_in[1];
    const float* bq = (const float*)d_in[2];
    const float* wk = (const float*)d_in[3];
    const float* bk = (const float*)d_in[4];
    const float* wv = (const float*)d_in[5];
    const float* bv = (const float*)d_in[6];

    unsigned short* A_pk = (unsigned short*)d_ws;                       // 50,331,648 B
    unsigned short* W_pk = A_pk + (size_t)A_TILES * TILE_ELEMS;         //  3,538,944 B
    float* biasb         = (float*)(W_pk + (size_t)W_TILES * TILE_ELEMS);

    hipLaunchKernelGGL(convert_pack, dim3(A_TILES + W_TILES), dim3(256), 0, stream,
                       hs, wq, wk, wv, bq, bk, bv, A_pk, W_pk, biasb);

    hipLaunchKernelGGL(qkv_gemm, dim3(NBLK), dim3(256), 0, stream,
                       A_pk, W_pk, biasb, (float*)d_out);
}